// Round 3
// baseline (569.448 us; speedup 1.0000x reference)
//
#include <hip/hip_runtime.h>
#include <hip/hip_bf16.h>
#include <math.h>

#define N_NODES 50000
#define N_EDGES 800000
#define HC      256   // H*C
#define SLOPE   0.2f
#define PB      782   // proj blocks = ceil(N_NODES/64)
#define GRID1   2048  // total K1 blocks (PB proj + 1266 edge-dot)

typedef __bf16 bf16x8 __attribute__((ext_vector_type(8)));
typedef float  f32x4  __attribute__((ext_vector_type(4)));

__device__ __forceinline__ unsigned short f2bf(float f) {
    unsigned u = __float_as_uint(f);
    unsigned r = (u + 0x7fffu + ((u >> 16) & 1u)) >> 16;
    return (unsigned short)r;
}

// ---------------------------------------------------------------------------
// K1-mega. Interleaved block roles so both kinds start immediately:
//   even blockIdx with (bid>>1)<PB  -> proj (h = x@W, a_src/a_dst, h_bf)
//   everything else                 -> edge-dot (v_t local, edge_ae in edge
//                                     order, workspace) + dst histogram
// Edge-dot work depends only on W_e/att_edge/edge_attr, so it overlaps proj.
__global__ __launch_bounds__(256) void k_mega(const float* __restrict__ x,
                                              const float* __restrict__ W,
                                              const float* __restrict__ att_src,
                                              const float* __restrict__ att_dst,
                                              const float* __restrict__ W_e,
                                              const float* __restrict__ att_edge,
                                              const int* __restrict__ ei,
                                              const float* __restrict__ edge_attr,
                                              unsigned short* __restrict__ h_bf,
                                              float* __restrict__ a_src,
                                              float* __restrict__ a_dst,
                                              float4* __restrict__ edge_ae,
                                              int* __restrict__ counts) {
    __shared__ unsigned short hs[64 * 256];   // 32 KB; edge blocks alias v_t here
    int t = threadIdx.x;
    int bid = blockIdx.x;
    int half = bid >> 1;
    bool is_proj = ((bid & 1) == 0) && (half < PB);

    if (!is_proj) {
        // ---------------- edge-dot + hist ----------------
        float* vtl = (float*)hs;              // 256 floats, j-major [4][64]
        {
            int k = t >> 2, jj = t & 3;       // t = k*4 + jj
            float s = 0.f;
            #pragma unroll
            for (int c = 0; c < 64; ++c)
                s += W_e[k * HC + jj * 64 + c] * att_edge[jj * 64 + c];
            vtl[jj * 64 + k] = s;
        }
        __syncthreads();
        int lane = t & 63;
        int sub = lane & 15;                  // 16 lanes per edge
        int eq = lane >> 4;                   // edge within quad
        float4 v0 = ((const float4*)(vtl +   0))[sub];
        float4 v1 = ((const float4*)(vtl +  64))[sub];
        float4 v2 = ((const float4*)(vtl + 128))[sub];
        float4 v3 = ((const float4*)(vtl + 192))[sub];
        int nb = GRID1 - PB;                  // 1266 edge blocks
        int eb = (bid & 1) ? half : (1024 + (half - PB));
        // dst-degree histogram (cnt pre-zeroed)
        for (int e = eb * 256 + t; e < N_EDGES; e += nb * 256)
            atomicAdd(&counts[ei[N_EDGES + e]], 1);
        int wave_id = eb * 4 + (t >> 6);
        int nwaves = nb * 4;
        const float4* ea4 = (const float4*)edge_attr;
        for (int g = wave_id; g < N_EDGES / 4; g += nwaves) {
            int e = g * 4 + eq;
            float4 ea = ea4[(size_t)e * 16 + sub];
            float p0 = ea.x * v0.x + ea.y * v0.y + ea.z * v0.z + ea.w * v0.w;
            float p1 = ea.x * v1.x + ea.y * v1.y + ea.z * v1.z + ea.w * v1.w;
            float p2 = ea.x * v2.x + ea.y * v2.y + ea.z * v2.z + ea.w * v2.w;
            float p3 = ea.x * v3.x + ea.y * v3.y + ea.z * v3.z + ea.w * v3.w;
            #pragma unroll
            for (int off = 1; off < 16; off <<= 1) {
                p0 += __shfl_xor(p0, off);
                p1 += __shfl_xor(p1, off);
                p2 += __shfl_xor(p2, off);
                p3 += __shfl_xor(p3, off);
            }
            if (sub == 0)                     // 4 lanes store 64B contiguous
                edge_ae[e] = make_float4(p0, p1, p2, p3);
        }
        return;
    }

    // ---------------- proj (split-bf16 MFMA, exact-ish fp32) ----------------
    int lane = t & 63;
    int w = t >> 6;                 // wave == head j
    int l15 = lane & 15;
    int quad = lane >> 4;
    int row0 = half * 64;

    bf16x8 bh[8], bl[8];            // frag index = ct*2 + ks
    #pragma unroll
    for (int ct = 0; ct < 4; ++ct) {
        #pragma unroll
        for (int ks = 0; ks < 2; ++ks) {
            bf16x8 h8, l8;
            #pragma unroll
            for (int j = 0; j < 8; ++j) {
                float f = W[(ks * 32 + quad * 8 + j) * 256 + w * 64 + ct * 16 + l15];
                __bf16 hi = (__bf16)f;
                h8[j] = hi;
                l8[j] = (__bf16)(f - (float)hi);
            }
            bh[ct * 2 + ks] = h8;
            bl[ct * 2 + ks] = l8;
        }
    }
    float att_s[4], att_d[4];
    #pragma unroll
    for (int ct = 0; ct < 4; ++ct) {
        att_s[ct] = att_src[w * 64 + ct * 16 + l15];
        att_d[ct] = att_dst[w * 64 + ct * 16 + l15];
    }

    #pragma unroll
    for (int rt = 0; rt < 4; ++rt) {
        int row_a = row0 + rt * 16 + l15;
        if (row_a >= N_NODES) row_a = N_NODES - 1;   // dup-load, store guarded
        bf16x8 ah[2], al[2];
        #pragma unroll
        for (int ks = 0; ks < 2; ++ks) {
            const float* xp = x + (size_t)row_a * 64 + ks * 32 + quad * 8;
            float4 x0 = ((const float4*)xp)[0];
            float4 x1 = ((const float4*)xp)[1];
            float xf[8] = {x0.x, x0.y, x0.z, x0.w, x1.x, x1.y, x1.z, x1.w};
            bf16x8 h8, l8;
            #pragma unroll
            for (int j = 0; j < 8; ++j) {
                __bf16 hi = (__bf16)xf[j];
                h8[j] = hi;
                l8[j] = (__bf16)(xf[j] - (float)hi);
            }
            ah[ks] = h8;
            al[ks] = l8;
        }
        f32x4 acc[4];
        #pragma unroll
        for (int ct = 0; ct < 4; ++ct) {
            f32x4 a = {0.f, 0.f, 0.f, 0.f};
            a = __builtin_amdgcn_mfma_f32_16x16x32_bf16(ah[0], bh[ct*2+0], a, 0, 0, 0);
            a = __builtin_amdgcn_mfma_f32_16x16x32_bf16(ah[1], bh[ct*2+1], a, 0, 0, 0);
            a = __builtin_amdgcn_mfma_f32_16x16x32_bf16(ah[0], bl[ct*2+0], a, 0, 0, 0);
            a = __builtin_amdgcn_mfma_f32_16x16x32_bf16(ah[1], bl[ct*2+1], a, 0, 0, 0);
            a = __builtin_amdgcn_mfma_f32_16x16x32_bf16(al[0], bh[ct*2+0], a, 0, 0, 0);
            a = __builtin_amdgcn_mfma_f32_16x16x32_bf16(al[1], bh[ct*2+1], a, 0, 0, 0);
            acc[ct] = a;
        }
        #pragma unroll
        for (int ct = 0; ct < 4; ++ct) {
            #pragma unroll
            for (int reg = 0; reg < 4; ++reg) {
                int r = rt * 16 + quad * 4 + reg;
                hs[r * 256 + (ct * 16 + l15) * 4 + w] = f2bf(acc[ct][reg]);
            }
        }
        #pragma unroll
        for (int reg = 0; reg < 4; ++reg) {
            float ps = 0.f, pd = 0.f;
            #pragma unroll
            for (int ct = 0; ct < 4; ++ct) {
                ps += acc[ct][reg] * att_s[ct];
                pd += acc[ct][reg] * att_d[ct];
            }
            #pragma unroll
            for (int off = 1; off < 16; off <<= 1) {
                ps += __shfl_xor(ps, off);
                pd += __shfl_xor(pd, off);
            }
            int row = row0 + rt * 16 + quad * 4 + reg;
            if (l15 == 0 && row < N_NODES) {
                a_src[row * 4 + w] = ps;
                a_dst[row * 4 + w] = pd;
            }
        }
    }
    __syncthreads();
    const uint4* ls = (const uint4*)hs;
    uint4* gd = (uint4*)h_bf;
    #pragma unroll
    for (int i = 0; i < 8; ++i) {
        int g = i * 256 + t;
        int rl = g >> 5;                       // 32 uint4 per row
        if (row0 + rl < N_NODES)
            gd[(size_t)row0 * 32 + g] = ls[g];
    }
}

// ---------------------------------------------------------------------------
// K2: single-block (1024 thr = 16 waves) coalesced scan: cnt -> rowptr, cursor.
__global__ __launch_bounds__(1024) void k_scan(const int* __restrict__ cnt,
                                               int* __restrict__ rowptr,
                                               int* __restrict__ cursor) {
    __shared__ int wsum[16];
    int t = threadIdx.x, lane = t & 63, w = t >> 6;
    const int WR = (N_NODES + 15) / 16;        // 3125 per wave
    int begin = w * WR;
    int end = begin + WR; if (end > N_NODES) end = N_NODES;
    int s = 0;
    for (int i = begin + lane; i < end; i += 64) s += cnt[i];
    #pragma unroll
    for (int off = 32; off >= 1; off >>= 1) s += __shfl_xor(s, off);
    if (lane == 0) wsum[w] = s;
    __syncthreads();
    if (t < 16) {
        int orig = wsum[t];
        int v = orig;
        #pragma unroll
        for (int off = 1; off < 16; off <<= 1) {
            int u = __shfl_up(v, off);
            if (t >= off) v += u;
        }
        wsum[t] = v - orig;                    // exclusive wave base
    }
    __syncthreads();
    int run = wsum[w];
    int nwin = (end - begin + 63) / 64;
    for (int win = 0; win < nwin; ++win) {
        int i = begin + win * 64 + lane;
        int c = (i < end) ? cnt[i] : 0;
        int v = c;
        #pragma unroll
        for (int off = 1; off < 64; off <<= 1) {
            int u = __shfl_up(v, off);
            if (lane >= off) v += u;
        }
        int excl = run + v - c;
        if (i < end) { rowptr[i] = excl; cursor[i] = excl; }
        run += __shfl(v, 63);
    }
    if (t == 0) rowptr[N_NODES] = N_EDGES;
}

// ---------------------------------------------------------------------------
// K3: light all-lane permutation pass: (src, eid) into dst-sorted slots.
// Reads coalesced ei; 2x 4B random stores + 1 atomic per edge.
__global__ __launch_bounds__(256) void k_scatter(const int* __restrict__ ei,
                                                 int* __restrict__ cursor,
                                                 int* __restrict__ ssrc,
                                                 int* __restrict__ seid) {
    int e = blockIdx.x * 256 + threadIdx.x;
    if (e >= N_EDGES) return;
    int dst = ei[N_EDGES + e];
    int src = ei[e];
    int p = atomicAdd(&cursor[dst], 1);
    ssrc[p] = src;
    seid[p] = e;
}

// ---------------------------------------------------------------------------
// K4: one wave per node (round-1-verified numeric path). Coalesced ssrc/seid
// preload, edge_ae via eid (random 16B, L2-resident 12.8MB), shfl-broadcast
// h-gather loop; self-loop fused; out written once. No atomics.
__global__ __launch_bounds__(256) void k_gather(const int* __restrict__ rowptr,
                                                const int* __restrict__ ssrc,
                                                const int* __restrict__ seid,
                                                const float4* __restrict__ edge_ae,
                                                const unsigned short* __restrict__ h_bf,
                                                const float* __restrict__ a_src,
                                                const float* __restrict__ a_dst,
                                                const float* __restrict__ bias,
                                                float* __restrict__ out) {
    int wave = (int)((blockIdx.x * 256u + threadIdx.x) >> 6);
    int lane = threadIdx.x & 63;
    if (wave >= N_NODES) return;
    int n = wave;
    int r0 = rowptr[n];
    int r1 = rowptr[n + 1];
    float4 ad = ((const float4*)a_dst)[n];
    const uint2* h2 = (const uint2*)h_bf;       // h2[n*64 + c] = 4 bf16 heads
    float a0 = 0.f, a1 = 0.f, a2 = 0.f, a3 = 0.f;
    float z0 = 0.f, z1 = 0.f, z2 = 0.f, z3 = 0.f;
    float s0 = 0.f, s1 = 0.f, s2 = 0.f, s3 = 0.f;
    for (int base = r0; base < r1; base += 64) {
        int cnt = r1 - base; if (cnt > 64) cnt = 64;
        int idx = base + (lane < cnt ? lane : 0);
        int msrc = ssrc[idx];                   // coalesced
        int eid  = seid[idx];                   // coalesced
        float4 ae = edge_ae[eid];               // random 16B, L2-resident
        float4 asv = ((const float4*)a_src)[msrc];  // random 16B, L2-resident
        float l0 = ae.x + asv.x + ad.x, l1 = ae.y + asv.y + ad.y;
        float l2 = ae.z + asv.z + ad.z, l3 = ae.w + asv.w + ad.w;
        l0 = fmaxf(l0, SLOPE * l0); l1 = fmaxf(l1, SLOPE * l1);
        l2 = fmaxf(l2, SLOPE * l2); l3 = fmaxf(l3, SLOPE * l3);
        float mw0 = __expf(l0), mw1 = __expf(l1);
        float mw2 = __expf(l2), mw3 = __expf(l3);
        if (lane < cnt) {
            z0 += mw0; z1 += mw1; z2 += mw2; z3 += mw3;
            s0 += ae.x; s1 += ae.y; s2 += ae.z; s3 += ae.w;
        }
        #pragma unroll 8
        for (int j = 0; j < cnt; ++j) {
            int src = __shfl(msrc, j);
            float e0 = __shfl(mw0, j), e1 = __shfl(mw1, j);
            float e2 = __shfl(mw2, j), e3 = __shfl(mw3, j);
            uint2 hv = h2[(size_t)src * 64 + lane];   // coalesced 512B/wave
            float h0 = __uint_as_float(hv.x << 16);
            float h1 = __uint_as_float(hv.x & 0xffff0000u);
            float h2f = __uint_as_float(hv.y << 16);
            float h3 = __uint_as_float(hv.y & 0xffff0000u);
            a0 += h0 * e0; a1 += h1 * e1; a2 += h2f * e2; a3 += h3 * e3;
        }
    }
    // reduce z / sumae across the wave
    #pragma unroll
    for (int off = 32; off >= 1; off >>= 1) {
        z0 += __shfl_xor(z0, off); z1 += __shfl_xor(z1, off);
        z2 += __shfl_xor(z2, off); z3 += __shfl_xor(z3, off);
        s0 += __shfl_xor(s0, off); s1 += __shfl_xor(s1, off);
        s2 += __shfl_xor(s2, off); s3 += __shfl_xor(s3, off);
    }
    // self loop: a_edge_self = sumae / max(deg,1)
    float d = (float)(r1 - r0); if (d < 1.f) d = 1.f;
    float rdeg = 1.f / d;
    float4 la = ((const float4*)a_src)[n];
    float l0 = la.x + ad.x + s0 * rdeg;
    float l1 = la.y + ad.y + s1 * rdeg;
    float l2 = la.z + ad.z + s2 * rdeg;
    float l3 = la.w + ad.w + s3 * rdeg;
    l0 = fmaxf(l0, SLOPE * l0); l1 = fmaxf(l1, SLOPE * l1);
    l2 = fmaxf(l2, SLOPE * l2); l3 = fmaxf(l3, SLOPE * l3);
    float w0 = __expf(l0), w1 = __expf(l1), w2 = __expf(l2), w3 = __expf(l3);
    uint2 hv = h2[(size_t)n * 64 + lane];
    float h0 = __uint_as_float(hv.x << 16);
    float h1 = __uint_as_float(hv.x & 0xffff0000u);
    float h2f = __uint_as_float(hv.y << 16);
    float h3 = __uint_as_float(hv.y & 0xffff0000u);
    a0 += h0 * w0; z0 += w0;
    a1 += h1 * w1; z1 += w1;
    a2 += h2f * w2; z2 += w2;
    a3 += h3 * w3; z3 += w3;
    size_t ob = (size_t)n * HC + lane;
    out[ob]       = a0 / (z0 + 1e-16f) + bias[lane];
    out[ob + 64]  = a1 / (z1 + 1e-16f) + bias[64 + lane];
    out[ob + 128] = a2 / (z2 + 1e-16f) + bias[128 + lane];
    out[ob + 192] = a3 / (z3 + 1e-16f) + bias[192 + lane];
}

// ---------------------------------------------------------------------------
extern "C" void kernel_launch(void* const* d_in, const int* in_sizes, int n_in,
                              void* d_out, int out_size, void* d_ws, size_t ws_size,
                              hipStream_t stream) {
    const float* x        = (const float*)d_in[0];
    const int*   ei       = (const int*)d_in[1];   // (2,E) int32
    const float* edge_attr= (const float*)d_in[2];
    const float* W        = (const float*)d_in[3];
    const float* W_e      = (const float*)d_in[4];
    const float* att_src  = (const float*)d_in[5];
    const float* att_dst  = (const float*)d_in[6];
    const float* att_edge = (const float*)d_in[7];
    const float* bias     = (const float*)d_in[8];
    float* out = (float*)d_out;

    // workspace layout (~47 MB total)
    unsigned short* h_bf  = (unsigned short*)d_ws;             // N*256 bf16 = 25.6 MB
    float*  a_src     = (float*)(h_bf + (size_t)N_NODES * 256);// N*4
    float*  a_dst     = a_src + N_NODES * 4;                   // N*4
    float4* edge_ae   = (float4*)(a_dst + N_NODES * 4);        // E float4 (12.8 MB), edge order
    int*    ssrc      = (int*)(edge_ae + N_EDGES);             // E dst-sorted src ids
    int*    seid      = ssrc + N_EDGES;                        // E dst-sorted edge ids
    int*    rowptr    = seid + N_EDGES;                        // N+1
    int*    cursor    = rowptr + N_NODES + 1;                  // N
    int*    cnt       = cursor + N_NODES;                      // N (zeroed)

    hipMemsetAsync(cnt, 0, (size_t)N_NODES * sizeof(int), stream);

    k_mega<<<GRID1, 256, 0, stream>>>(x, W, att_src, att_dst, W_e, att_edge,
                                      ei, edge_attr, h_bf, a_src, a_dst,
                                      edge_ae, cnt);
    k_scan<<<1, 1024, 0, stream>>>(cnt, rowptr, cursor);
    k_scatter<<<(N_EDGES + 255) / 256, 256, 0, stream>>>(ei, cursor, ssrc, seid);
    k_gather<<<(N_NODES + 3) / 4, 256, 0, stream>>>(rowptr, ssrc, seid, edge_ae,
                                                    h_bf, a_src, a_dst,
                                                    bias, out);
}

// Round 4
// 495.354 us; speedup vs baseline: 1.1496x; 1.1496x over previous
//
#include <hip/hip_runtime.h>
#include <hip/hip_bf16.h>
#include <math.h>

#define N_NODES 50000
#define N_EDGES 800000
#define HC      256   // H*C
#define SLOPE   0.2f

typedef __bf16 bf16x8 __attribute__((ext_vector_type(8)));
typedef float  f32x4  __attribute__((ext_vector_type(4)));

__device__ __forceinline__ unsigned short f2bf(float f) {
    unsigned u = __float_as_uint(f);
    unsigned r = (u + 0x7fffu + ((u >> 16) & 1u)) >> 16;
    return (unsigned short)r;
}

__device__ __forceinline__ float rlane_f(float v, int j) {
    return __uint_as_float((unsigned)__builtin_amdgcn_readlane((int)__float_as_uint(v), j));
}

// ---------------------------------------------------------------------------
// K1: h = x @ W via split-bf16 MFMA (hi*hi + hi*lo + lo*hi ~= fp32 exact).
// Block = 4 waves = 64 rows x 256 cols; wave w owns cols [w*64, w*64+64).
// Fused: block 0 also computes v_t (edge-attn vector), and all blocks do the
// dst-degree histogram (was a separate serial dispatch).
__global__ __launch_bounds__(256) void k_proj(const float* __restrict__ x,
                                              const float* __restrict__ W,
                                              const float* __restrict__ att_src,
                                              const float* __restrict__ att_dst,
                                              const float* __restrict__ W_e,
                                              const float* __restrict__ att_edge,
                                              const int* __restrict__ ei,
                                              unsigned short* __restrict__ h_bf,
                                              float* __restrict__ a_src,
                                              float* __restrict__ a_dst,
                                              float* __restrict__ v_t,
                                              int* __restrict__ counts) {
    // --- fused K_vedge: v_t[j][k] = sum_c W_e[k][j*64+c] * att_edge[j][c] ---
    if (blockIdx.x == 0) {
        int tt = threadIdx.x;         // tt = k*4 + j
        int k = tt >> 2, jj = tt & 3;
        float s = 0.f;
        #pragma unroll
        for (int c = 0; c < 64; ++c)
            s += W_e[k * HC + jj * 64 + c] * att_edge[jj * 64 + c];
        v_t[jj * 64 + k] = s;
    }
    // --- fused K_hist: dst-degree histogram (cnt pre-zeroed by memset) ---
    for (int e = blockIdx.x * 256 + threadIdx.x; e < N_EDGES;
         e += gridDim.x * 256)
        atomicAdd(&counts[ei[N_EDGES + e]], 1);

    __shared__ unsigned short hs[64 * 256];   // 32 KB, mirrors global layout
    int t = threadIdx.x;
    int lane = t & 63;
    int w = t >> 6;                 // wave == head j
    int l15 = lane & 15;
    int quad = lane >> 4;
    int row0 = blockIdx.x * 64;

    bf16x8 bh[8], bl[8];            // frag index = ct*2 + ks
    #pragma unroll
    for (int ct = 0; ct < 4; ++ct) {
        #pragma unroll
        for (int ks = 0; ks < 2; ++ks) {
            bf16x8 h8, l8;
            #pragma unroll
            for (int j = 0; j < 8; ++j) {
                float f = W[(ks * 32 + quad * 8 + j) * 256 + w * 64 + ct * 16 + l15];
                __bf16 hi = (__bf16)f;
                h8[j] = hi;
                l8[j] = (__bf16)(f - (float)hi);
            }
            bh[ct * 2 + ks] = h8;
            bl[ct * 2 + ks] = l8;
        }
    }
    float att_s[4], att_d[4];
    #pragma unroll
    for (int ct = 0; ct < 4; ++ct) {
        att_s[ct] = att_src[w * 64 + ct * 16 + l15];
        att_d[ct] = att_dst[w * 64 + ct * 16 + l15];
    }

    #pragma unroll
    for (int rt = 0; rt < 4; ++rt) {
        int row_a = row0 + rt * 16 + l15;
        if (row_a >= N_NODES) row_a = N_NODES - 1;   // dup-load, store guarded
        bf16x8 ah[2], al[2];
        #pragma unroll
        for (int ks = 0; ks < 2; ++ks) {
            const float* xp = x + (size_t)row_a * 64 + ks * 32 + quad * 8;
            float4 x0 = ((const float4*)xp)[0];
            float4 x1 = ((const float4*)xp)[1];
            float xf[8] = {x0.x, x0.y, x0.z, x0.w, x1.x, x1.y, x1.z, x1.w};
            bf16x8 h8, l8;
            #pragma unroll
            for (int j = 0; j < 8; ++j) {
                __bf16 hi = (__bf16)xf[j];
                h8[j] = hi;
                l8[j] = (__bf16)(xf[j] - (float)hi);
            }
            ah[ks] = h8;
            al[ks] = l8;
        }
        f32x4 acc[4];
        #pragma unroll
        for (int ct = 0; ct < 4; ++ct) {
            f32x4 a = {0.f, 0.f, 0.f, 0.f};
            a = __builtin_amdgcn_mfma_f32_16x16x32_bf16(ah[0], bh[ct*2+0], a, 0, 0, 0);
            a = __builtin_amdgcn_mfma_f32_16x16x32_bf16(ah[1], bh[ct*2+1], a, 0, 0, 0);
            a = __builtin_amdgcn_mfma_f32_16x16x32_bf16(ah[0], bl[ct*2+0], a, 0, 0, 0);
            a = __builtin_amdgcn_mfma_f32_16x16x32_bf16(ah[1], bl[ct*2+1], a, 0, 0, 0);
            a = __builtin_amdgcn_mfma_f32_16x16x32_bf16(al[0], bh[ct*2+0], a, 0, 0, 0);
            a = __builtin_amdgcn_mfma_f32_16x16x32_bf16(al[1], bh[ct*2+1], a, 0, 0, 0);
            acc[ct] = a;
        }
        #pragma unroll
        for (int ct = 0; ct < 4; ++ct) {
            #pragma unroll
            for (int reg = 0; reg < 4; ++reg) {
                int r = rt * 16 + quad * 4 + reg;
                hs[r * 256 + (ct * 16 + l15) * 4 + w] = f2bf(acc[ct][reg]);
            }
        }
        #pragma unroll
        for (int reg = 0; reg < 4; ++reg) {
            float ps = 0.f, pd = 0.f;
            #pragma unroll
            for (int ct = 0; ct < 4; ++ct) {
                ps += acc[ct][reg] * att_s[ct];
                pd += acc[ct][reg] * att_d[ct];
            }
            #pragma unroll
            for (int off = 1; off < 16; off <<= 1) {
                ps += __shfl_xor(ps, off);
                pd += __shfl_xor(pd, off);
            }
            int row = row0 + rt * 16 + quad * 4 + reg;
            if (l15 == 0 && row < N_NODES) {
                a_src[row * 4 + w] = ps;
                a_dst[row * 4 + w] = pd;
            }
        }
    }
    __syncthreads();
    const uint4* ls = (const uint4*)hs;
    uint4* gd = (uint4*)h_bf;
    #pragma unroll
    for (int i = 0; i < 8; ++i) {
        int g = i * 256 + t;
        int rl = g >> 5;                       // 32 uint4 per row
        if (row0 + rl < N_NODES)
            gd[(size_t)row0 * 32 + g] = ls[g];
    }
}

// ---------------------------------------------------------------------------
// K2: single-block (1024 thr = 16 waves) coalesced scan: cnt -> rowptr, cursor.
__global__ __launch_bounds__(1024) void k_scan(const int* __restrict__ cnt,
                                               int* __restrict__ rowptr,
                                               int* __restrict__ cursor) {
    __shared__ int wsum[16];
    int t = threadIdx.x, lane = t & 63, w = t >> 6;
    const int WR = (N_NODES + 15) / 16;        // 3125 per wave
    int begin = w * WR;
    int end = begin + WR; if (end > N_NODES) end = N_NODES;
    int s = 0;
    for (int i = begin + lane; i < end; i += 64) s += cnt[i];
    #pragma unroll
    for (int off = 32; off >= 1; off >>= 1) s += __shfl_xor(s, off);
    if (lane == 0) wsum[w] = s;
    __syncthreads();
    if (t < 16) {
        int orig = wsum[t];
        int v = orig;
        #pragma unroll
        for (int off = 1; off < 16; off <<= 1) {
            int u = __shfl_up(v, off);
            if (t >= off) v += u;
        }
        wsum[t] = v - orig;                    // exclusive wave base
    }
    __syncthreads();
    int run = wsum[w];
    int nwin = (end - begin + 63) / 64;
    for (int win = 0; win < nwin; ++win) {
        int i = begin + win * 64 + lane;
        int c = (i < end) ? cnt[i] : 0;
        int v = c;
        #pragma unroll
        for (int off = 1; off < 64; off <<= 1) {
            int u = __shfl_up(v, off);
            if (lane >= off) v += u;
        }
        int excl = run + v - c;
        if (i < end) { rowptr[i] = excl; cursor[i] = excl; }
        run += __shfl(v, 63);
    }
    if (t == 0) rowptr[N_NODES] = N_EDGES;
}

// ---------------------------------------------------------------------------
// K3: streaming edge pass. 4 edges/wave/iter, float4 loads. Scatters the
// VALUES (raw edge-attn logit float4 + src id) directly into dst-sorted
// slots so K4's preload is fully coalesced (no eid indirection).
__global__ __launch_bounds__(256) void k_edge(const int* __restrict__ ei,
                                              const float* __restrict__ edge_attr,
                                              const float* __restrict__ v_t,
                                              int* __restrict__ cursor,
                                              int* __restrict__ ssrc,
                                              float4* __restrict__ sl4) {
    int t = threadIdx.x;
    int lane = t & 63;
    int sub = lane & 15;                    // 16 lanes per edge
    int eq = lane >> 4;                     // edge index within quad
    float4 v0 = ((const float4*)(v_t +   0))[sub];
    float4 v1 = ((const float4*)(v_t +  64))[sub];
    float4 v2 = ((const float4*)(v_t + 128))[sub];
    float4 v3 = ((const float4*)(v_t + 192))[sub];
    int wave_id = blockIdx.x * 4 + (t >> 6);
    int nwaves = gridDim.x * 4;
    const float4* ea4 = (const float4*)edge_attr;
    for (int g = wave_id; g < N_EDGES / 4; g += nwaves) {
        int e = g * 4 + eq;
        float4 ea = ea4[(size_t)e * 16 + sub];
        float p0 = ea.x * v0.x + ea.y * v0.y + ea.z * v0.z + ea.w * v0.w;
        float p1 = ea.x * v1.x + ea.y * v1.y + ea.z * v1.z + ea.w * v1.w;
        float p2 = ea.x * v2.x + ea.y * v2.y + ea.z * v2.z + ea.w * v2.w;
        float p3 = ea.x * v3.x + ea.y * v3.y + ea.z * v3.z + ea.w * v3.w;
        #pragma unroll
        for (int off = 1; off < 16; off <<= 1) {
            p0 += __shfl_xor(p0, off);
            p1 += __shfl_xor(p1, off);
            p2 += __shfl_xor(p2, off);
            p3 += __shfl_xor(p3, off);
        }
        if (sub == 0) {
            int dst = ei[N_EDGES + e];
            int src = ei[e];
            int p = atomicAdd(&cursor[dst], 1);
            ssrc[p] = src;
            sl4[p] = make_float4(p0, p1, p2, p3);
        }
    }
}

// ---------------------------------------------------------------------------
// K4: one wave per node. Preload fully coalesced (ssrc, sl4 dst-sorted) +
// one L2-resident random a_src gather. j-loop broadcast via v_readlane
// (uniform j -> SGPR) instead of ds_bpermute: scalar src gives an SGPR-based
// h address; broadcast values bit-identical to __shfl, so numerics match
// round 1 exactly. Self-loop fused; out written once. No atomics.
__global__ __launch_bounds__(256) void k_gather(const int* __restrict__ rowptr,
                                                const int* __restrict__ ssrc,
                                                const float4* __restrict__ sl4,
                                                const unsigned short* __restrict__ h_bf,
                                                const float* __restrict__ a_src,
                                                const float* __restrict__ a_dst,
                                                const float* __restrict__ bias,
                                                float* __restrict__ out) {
    int wave = (int)((blockIdx.x * 256u + threadIdx.x) >> 6);
    int lane = threadIdx.x & 63;
    if (wave >= N_NODES) return;
    int n = wave;
    int r0 = rowptr[n];
    int r1 = rowptr[n + 1];
    float4 ad = ((const float4*)a_dst)[n];
    const uint2* h2 = (const uint2*)h_bf;       // h2[n*64 + c] = 4 bf16 heads
    float a0 = 0.f, a1 = 0.f, a2 = 0.f, a3 = 0.f;
    float z0 = 0.f, z1 = 0.f, z2 = 0.f, z3 = 0.f;
    float s0 = 0.f, s1 = 0.f, s2 = 0.f, s3 = 0.f;
    for (int base = r0; base < r1; base += 64) {
        int cnt = r1 - base; if (cnt > 64) cnt = 64;
        int idx = base + (lane < cnt ? lane : 0);
        int msrc = ssrc[idx];                   // coalesced
        float4 ae = sl4[idx];                   // coalesced 16B
        float4 asv = ((const float4*)a_src)[msrc];  // random 16B, L2-resident
        float l0 = ae.x + asv.x + ad.x, l1 = ae.y + asv.y + ad.y;
        float l2 = ae.z + asv.z + ad.z, l3 = ae.w + asv.w + ad.w;
        l0 = fmaxf(l0, SLOPE * l0); l1 = fmaxf(l1, SLOPE * l1);
        l2 = fmaxf(l2, SLOPE * l2); l3 = fmaxf(l3, SLOPE * l3);
        float mw0 = __expf(l0), mw1 = __expf(l1);
        float mw2 = __expf(l2), mw3 = __expf(l3);
        if (lane < cnt) {
            z0 += mw0; z1 += mw1; z2 += mw2; z3 += mw3;
            s0 += ae.x; s1 += ae.y; s2 += ae.z; s3 += ae.w;
        }
        #pragma unroll 8
        for (int j = 0; j < cnt; ++j) {
            int src = __builtin_amdgcn_readlane(msrc, j);        // SGPR
            float e0 = rlane_f(mw0, j), e1 = rlane_f(mw1, j);
            float e2 = rlane_f(mw2, j), e3 = rlane_f(mw3, j);
            const uint2* hp = h2 + ((size_t)(unsigned)src << 6); // SGPR base
            uint2 hv = hp[lane];                 // coalesced 512B/wave
            float h0 = __uint_as_float(hv.x << 16);
            float h1 = __uint_as_float(hv.x & 0xffff0000u);
            float h2f = __uint_as_float(hv.y << 16);
            float h3 = __uint_as_float(hv.y & 0xffff0000u);
            a0 += h0 * e0; a1 += h1 * e1; a2 += h2f * e2; a3 += h3 * e3;
        }
    }
    // reduce z / sumae across the wave
    #pragma unroll
    for (int off = 32; off >= 1; off >>= 1) {
        z0 += __shfl_xor(z0, off); z1 += __shfl_xor(z1, off);
        z2 += __shfl_xor(z2, off); z3 += __shfl_xor(z3, off);
        s0 += __shfl_xor(s0, off); s1 += __shfl_xor(s1, off);
        s2 += __shfl_xor(s2, off); s3 += __shfl_xor(s3, off);
    }
    // self loop: a_edge_self = sumae / max(deg,1)
    float d = (float)(r1 - r0); if (d < 1.f) d = 1.f;
    float rdeg = 1.f / d;
    float4 la = ((const float4*)a_src)[n];
    float l0 = la.x + ad.x + s0 * rdeg;
    float l1 = la.y + ad.y + s1 * rdeg;
    float l2 = la.z + ad.z + s2 * rdeg;
    float l3 = la.w + ad.w + s3 * rdeg;
    l0 = fmaxf(l0, SLOPE * l0); l1 = fmaxf(l1, SLOPE * l1);
    l2 = fmaxf(l2, SLOPE * l2); l3 = fmaxf(l3, SLOPE * l3);
    float w0 = __expf(l0), w1 = __expf(l1), w2 = __expf(l2), w3 = __expf(l3);
    uint2 hv = h2[(size_t)n * 64 + lane];
    float h0 = __uint_as_float(hv.x << 16);
    float h1 = __uint_as_float(hv.x & 0xffff0000u);
    float h2f = __uint_as_float(hv.y << 16);
    float h3 = __uint_as_float(hv.y & 0xffff0000u);
    a0 += h0 * w0; z0 += w0;
    a1 += h1 * w1; z1 += w1;
    a2 += h2f * w2; z2 += w2;
    a3 += h3 * w3; z3 += w3;
    size_t ob = (size_t)n * HC + lane;
    out[ob]       = a0 / (z0 + 1e-16f) + bias[lane];
    out[ob + 64]  = a1 / (z1 + 1e-16f) + bias[64 + lane];
    out[ob + 128] = a2 / (z2 + 1e-16f) + bias[128 + lane];
    out[ob + 192] = a3 / (z3 + 1e-16f) + bias[192 + lane];
}

// ---------------------------------------------------------------------------
extern "C" void kernel_launch(void* const* d_in, const int* in_sizes, int n_in,
                              void* d_out, int out_size, void* d_ws, size_t ws_size,
                              hipStream_t stream) {
    const float* x        = (const float*)d_in[0];
    const int*   ei       = (const int*)d_in[1];   // (2,E) int32
    const float* edge_attr= (const float*)d_in[2];
    const float* W        = (const float*)d_in[3];
    const float* W_e      = (const float*)d_in[4];
    const float* att_src  = (const float*)d_in[5];
    const float* att_dst  = (const float*)d_in[6];
    const float* att_edge = (const float*)d_in[7];
    const float* bias     = (const float*)d_in[8];
    float* out = (float*)d_out;

    // workspace layout
    unsigned short* h_bf  = (unsigned short*)d_ws;             // N*256 bf16 = 25.6 MB
    float*  a_src     = (float*)(h_bf + (size_t)N_NODES * 256);// N*4
    float*  a_dst     = a_src + N_NODES * 4;                   // N*4
    float*  v_t       = a_dst + N_NODES * 4;                   // 256
    float4* sl4       = (float4*)(v_t + 256);                  // E float4 (12.8 MB) dst-sorted
    int*    ssrc      = (int*)(sl4 + N_EDGES);                 // E dst-sorted src ids
    int*    rowptr    = ssrc + N_EDGES;                        // N+1
    int*    cursor    = rowptr + N_NODES + 1;                  // N
    int*    cnt       = cursor + N_NODES;                      // N (zeroed)

    hipMemsetAsync(cnt, 0, (size_t)N_NODES * sizeof(int), stream);

    k_proj<<<(N_NODES + 63) / 64, 256, 0, stream>>>(x, W, att_src, att_dst,
                                                    W_e, att_edge, ei,
                                                    h_bf, a_src, a_dst, v_t, cnt);
    k_scan<<<1, 1024, 0, stream>>>(cnt, rowptr, cursor);
    k_edge<<<2048, 256, 0, stream>>>(ei, edge_attr, v_t, cursor, ssrc, sl4);
    k_gather<<<(N_NODES + 3) / 4, 256, 0, stream>>>(rowptr, ssrc, sl4,
                                                    h_bf, a_src, a_dst,
                                                    bias, out);
}